// Round 15
// baseline (320.621 us; speedup 1.0000x reference)
//
#include <hip/hip_runtime.h>
#include <hip/hip_bf16.h>
#include <stdint.h>

#define G 256
#define NPG 400
#define DEG 32
#define FIN 400
#define H 64
#define NN (G*NPG)        // 102400
#define EE (G*NPG*DEG)    // 3276800
#define EPG (NPG*DEG)     // 12800 edges per graph
#define CPG (EPG+NPG)     // 13200 entries per graph (edges + self loops)
#define NTILE 25          // 16-row dst tiles per graph (25x16 = 400 exactly)
#define ATS 420           // A-tile LDS stride (floats)
#define HTS 72            // h-tile LDS stride (halves)
#define MTF 26624         // per-graph M fragment-order elems: 4nt*13ks*64lane*8j

// wf buffer layout (halves)
#define W1F_OFF 0
#define W1F_N   (13*4*64*8)          // 26624
#define W2F_OFF (W1F_OFF + W1F_N)    // 26624
#define W2F_N   (2*4*64*8)           // 4096
#define W3F_OFF (W2F_OFF + W2F_N)    // 30720
#define WCF_OFF (W3F_OFF + W2F_N)    // 34816
#define WCF_N   (832*4*64*8)         // 1703936  (K' = 26624 = 832 kt-chunks)
#define WF_TOT  (WCF_OFF + WCF_N)    // 1738752 = 1698*1024 exactly

typedef __attribute__((ext_vector_type(8))) _Float16 h8;
typedef __attribute__((ext_vector_type(4))) float f32x4;

static __device__ __forceinline__ unsigned packh2(float a, float b) {
  unsigned short ua = __builtin_bit_cast(unsigned short, (_Float16)a);
  unsigned short ub = __builtin_bit_cast(unsigned short, (_Float16)b);
  return (unsigned)ua | ((unsigned)ub << 16);
}

static __device__ __forceinline__ h8 cvt8(float4 a, float4 b) {
  h8 r;
  r[0] = (_Float16)a.x; r[1] = (_Float16)a.y; r[2] = (_Float16)a.z; r[3] = (_Float16)a.w;
  r[4] = (_Float16)b.x; r[5] = (_Float16)b.y; r[6] = (_Float16)b.z; r[7] = (_Float16)b.w;
  return r;
}

// ---------------- kFront: kNorm (b<256) | weight pack (b>=256) | zero gbuf/cnt
__global__ __launch_bounds__(1024) void kFront(
    const int* __restrict__ ei, const float* __restrict__ ew,
    const float* __restrict__ W1, const float* __restrict__ W2,
    const float* __restrict__ W3, const float* __restrict__ Wc,
    uint32_t* __restrict__ ent, uint32_t* __restrict__ boff,
    _Float16* __restrict__ wf, float* __restrict__ gbuf, uint32_t* __restrict__ cnt)
{
  __shared__ float deg[NPG];
  __shared__ float dv[NPG];
  __shared__ uint32_t bcnt[32], bpos[32];
  const int b = blockIdx.x, tid = threadIdx.x;

  if (b >= 256) {
    // ---- pack role: one element per thread ----
    int idx = (b - 256)*1024 + tid;            // < WF_TOT exactly
    if (idx < G*H) gbuf[idx] = 0.f;
    if (idx == 0) *cnt = 0u;
    if (idx < W2F_OFF) {                       // W1: [ks 13][nt 4][lane][j]
      int i = idx;
      int j = i & 7, ln = (i >> 3) & 63, nt = (i >> 9) & 3, ks = i >> 11;
      int k = ks*32 + (ln >> 4)*8 + j, col = nt*16 + (ln & 15);
      wf[idx] = (k < FIN) ? (_Float16)W1[k*H + col] : (_Float16)0.f;
    } else if (idx < W3F_OFF) {                // W2: [ks 2][nt 4][lane][j]
      int i = idx - W2F_OFF;
      int j = i & 7, ln = (i >> 3) & 63, nt = (i >> 9) & 3, ks = i >> 11;
      wf[idx] = (_Float16)W2[(ks*32 + (ln >> 4)*8 + j)*H + nt*16 + (ln & 15)];
    } else if (idx < WCF_OFF) {                // W3
      int i = idx - W3F_OFF;
      int j = i & 7, ln = (i >> 3) & 63, nt = (i >> 9) & 3, ks = i >> 11;
      wf[idx] = (_Float16)W3[(ks*32 + (ln >> 4)*8 + j)*H + nt*16 + (ln & 15)];
    } else {                                   // Wc, k' = mtF flat index
      int i = idx - WCF_OFF;
      int j = i & 7, ln = (i >> 3) & 63, ntc = (i >> 9) & 3, kt = i >> 11;
      int kp = kt*32 + (ln >> 4)*8 + j;        // 0..26623 (mtF flat)
      int nt_m = kp / 6656, rem = kp % 6656;   // 6656 = 13*512
      int ks_m = rem >> 9, rem2 = rem & 511;
      int lane_m = rem2 >> 3, j_m = rem2 & 7;
      int node = ks_m*32 + (lane_m >> 4)*8 + j_m;
      int feat = nt_m*16 + (lane_m & 15);
      int col = ntc*16 + (ln & 15);
      wf[idx] = (node < NPG) ? (_Float16)Wc[((size_t)node*64 + feat)*64 + col]
                             : (_Float16)0.f;
    }
    return;
  }

  // ---- norm role: degree + packed 4B entries bucketed by 16-row tile ----
  // entry = dstLocal[29:26] | src[25:16] | fp16(norm)[15:0]
  const int g = b;
  const int ebase = g*EPG, nbase = g*NPG;
  const int* rowp = ei;          // sources
  const int* colp = ei + EE;     // targets
  if (tid < NTILE) bcnt[tid] = 0u;
  for (int v = tid; v < NPG; v += 1024) deg[v] = 1.0f;   // self-loop weight
  __syncthreads();
  for (int e = tid; e < EPG; e += 1024) {
    int c = colp[ebase+e] - nbase;
    atomicAdd(&deg[c], ew[ebase+e]);
    atomicAdd(&bcnt[c >> 4], 1u);
  }
  __syncthreads();
  for (int v = tid; v < NPG; v += 1024) dv[v] = rsqrtf(deg[v]);
  if (tid == 0) {
    uint32_t s = 0;
    #pragma unroll
    for (int t = 0; t < NTILE; ++t) {
      uint32_t c = bcnt[t] + 16u;              // + 16 self loops per tile
      bcnt[t] = s; bpos[t] = s; s += c;
    }
  }
  __syncthreads();
  if (tid < NTILE) boff[g*32 + tid] = bcnt[tid];
  if (tid == NTILE) boff[g*32 + NTILE] = (uint32_t)CPG;
  uint32_t* eb = ent + (size_t)g*CPG;
  for (int e = tid; e < EPG; e += 1024) {
    int src = rowp[ebase+e] - nbase;
    int dst = colp[ebase+e] - nbase;
    float nm = dv[src] * ew[ebase+e] * dv[dst];
    unsigned short nb = __builtin_bit_cast(unsigned short, (_Float16)nm);
    uint32_t p = atomicAdd(&bpos[dst >> 4], 1u);
    eb[p] = ((unsigned)(dst & 15) << 26) | ((unsigned)src << 16) | nb;
  }
  for (int v = tid; v < NPG; v += 1024) {
    float nm = dv[v]*dv[v];
    unsigned short nb = __builtin_bit_cast(unsigned short, (_Float16)nm);
    uint32_t p = atomicAdd(&bpos[v >> 4], 1u);
    eb[p] = ((unsigned)(v & 15) << 26) | ((unsigned)v << 16) | nb;
  }
}

// ---------------- kM1: mtF1 = frag-order (x @ W1), fp16, no LDS --------------
__global__ __launch_bounds__(256, 8) void kM1(
    const float* __restrict__ x, const _Float16* __restrict__ wf,
    _Float16* __restrict__ mt1)
{
  const int tid = threadIdx.x, lane = tid & 63, wave = tid >> 6;
  const int l15 = lane & 15, kgrp = lane >> 4;
  const int g = blockIdx.y, b = blockIdx.x;  // b < 7, nodes b*64..b*64+63
  const int node_l = b*64 + wave*16 + l15;
  const int arow = (node_l < NPG) ? node_l : NPG-1;
  const float* xp = x + ((size_t)g*NPG + arow)*FIN;

  f32x4 acc[4] = {{0,0,0,0},{0,0,0,0},{0,0,0,0},{0,0,0,0}};
  for (int ks = 0; ks < 13; ++ks) {
    const int kb = ks*32 + kgrp*8;
    h8 af;
    if (kb + 8 <= FIN) {
      float4 a0 = *(const float4*)(xp + kb);
      float4 a1 = *(const float4*)(xp + kb + 4);
      af = cvt8(a0, a1);
    } else {
      h8 z;
      #pragma unroll
      for (int j = 0; j < 8; ++j) z[j] = (_Float16)0.f;
      af = z;
    }
    #pragma unroll
    for (int nt = 0; nt < 4; ++nt) {
      h8 bf = *(const h8*)&wf[W1F_OFF + (((size_t)ks*4 + nt)*64 + lane)*8];
      acc[nt] = __builtin_amdgcn_mfma_f32_16x16x32_f16(af, bf, acc[nt], 0, 0, 0);
    }
  }
  // direct fragment-order write: D row = kgrp*4+r -> node; col = nt*16+l15
  const int nd0 = b*64 + wave*16 + kgrp*4;
  if (nd0 < NPG) {
    const int ksw = nd0 >> 5, lh = (nd0 >> 3) & 3, jb = nd0 & 7;
    _Float16* mb = mt1 + (size_t)g*MTF;
    #pragma unroll
    for (int nt = 0; nt < 4; ++nt) {
      uint2 u;
      u.x = packh2(acc[nt][0], acc[nt][1]);
      u.y = packh2(acc[nt][2], acc[nt][3]);
      *(uint2*)&mb[(((size_t)nt*13 + ksw)*64 + lh*16 + l15)*8 + jb] = u;
    }
  }
}

// ---------------- kAgg<WMUL>: one 16-row dst tile: scatter + agg MFMA --------
template<int WMUL>
__global__ __launch_bounds__(256, 5) void kAgg(
    const _Float16* __restrict__ mtin, const _Float16* __restrict__ wfn,
    const float* __restrict__ bias,
    const uint32_t* __restrict__ ent, const uint32_t* __restrict__ boff,
    _Float16* __restrict__ out)
{
  extern __shared__ char smem[];
  float* sAT = (float*)smem;                     // 16*420*4 = 26880 B
  _Float16* sh = (_Float16*)(smem + 16*ATS*4);   // 16*72*2  = 2304 B
  const int tid = threadIdx.x, lane = tid & 63;
  const int l15 = lane & 15, kgrp = lane >> 4;
  const int bid = blockIdx.x;
  const int g = bid & 255, t = bid >> 8;         // same-graph blocks share XCD
  const int nt = tid >> 6;                       // wave = output col quarter
  const uint32_t* eb = ent + (size_t)g*CPG;
  const uint32_t s0 = boff[g*32 + t], s1 = boff[g*32 + t + 1];

  // coalesced BF prefetch: 13 x 1KB wave loads (frag-order mt)
  h8 BF[13];
  const _Float16* mrow = mtin + (size_t)g*MTF + (size_t)nt*13*512 + lane*8;
  #pragma unroll
  for (int ks = 0; ks < 13; ++ks)
    BF[ks] = *(const h8*)(mrow + ks*512);
  const float bv = bias[nt*16 + l15];
  h8 WF2[2];
  if (WMUL) {
    WF2[0] = *(const h8*)&wfn[((size_t)(0*4 + nt)*64 + lane)*8];
    WF2[1] = *(const h8*)&wfn[((size_t)(1*4 + nt)*64 + lane)*8];
  }
  const uint32_t e0 = s0 + tid;
  uint32_t E0 = 0, E1 = 0, E2 = 0;
  bool p0 = e0 < s1, p1 = e0 + 256 < s1, p2 = e0 + 512 < s1;
  if (p0) E0 = eb[e0];
  if (p1) E1 = eb[e0 + 256];
  if (p2) E2 = eb[e0 + 512];

  // zero A-tile
  { float4* p = (float4*)sAT;
    for (int i = tid; i < 16*ATS/4; i += 256) p[i] = make_float4(0,0,0,0); }
  __syncthreads();

  // scatter: addr = dstLocal*ATS + src, weight = fp16 bits
  if (p0) atomicAdd(&sAT[(int)(E0 >> 26)*ATS + (int)((E0 >> 16) & 0x3FFu)],
                    (float)__builtin_bit_cast(_Float16, (unsigned short)(E0 & 0xFFFFu)));
  if (p1) atomicAdd(&sAT[(int)(E1 >> 26)*ATS + (int)((E1 >> 16) & 0x3FFu)],
                    (float)__builtin_bit_cast(_Float16, (unsigned short)(E1 & 0xFFFFu)));
  if (p2) atomicAdd(&sAT[(int)(E2 >> 26)*ATS + (int)((E2 >> 16) & 0x3FFu)],
                    (float)__builtin_bit_cast(_Float16, (unsigned short)(E2 & 0xFFFFu)));
  for (uint32_t e = e0 + 768; e < s1; e += 256) {      // overflow guard
    uint32_t E = eb[e];
    atomicAdd(&sAT[(int)(E >> 26)*ATS + (int)((E >> 16) & 0x3FFu)],
              (float)__builtin_bit_cast(_Float16, (unsigned short)(E & 0xFFFFu)));
  }
  __syncthreads();

  // agg MFMA: 16 nodes x 16 cols per wave
  f32x4 acc = {0,0,0,0};
  const float* ap = &sAT[l15*ATS];
  #pragma unroll
  for (int ks = 0; ks < 13; ++ks) {
    int kb = ks*32 + kgrp*8;
    float4 a0 = *(const float4*)(ap + kb);
    float4 a1 = *(const float4*)(ap + kb + 4);
    acc = __builtin_amdgcn_mfma_f32_16x16x32_f16(cvt8(a0, a1), BF[ks], acc, 0, 0, 0);
  }

  // fragment-order write coords for output node block
  const int nd0 = t*16 + kgrp*4;               // < 400 always
  const int ksw = nd0 >> 5, lh = (nd0 >> 3) & 3, jb = nd0 & 7;
  _Float16* ob = out + (size_t)g*MTF;

  if (!WMUL) {
    uint2 u;
    u.x = packh2(acc[0] + bv, acc[1] + bv);
    u.y = packh2(acc[2] + bv, acc[3] + bv);
    *(uint2*)&ob[(((size_t)nt*13 + ksw)*64 + lh*16 + l15)*8 + jb] = u;
  } else {
    // bias + relu -> h-tile LDS
    #pragma unroll
    for (int r = 0; r < 4; ++r)
      sh[(kgrp*4 + r)*HTS + nt*16 + l15] = (_Float16)fmaxf(acc[r] + bv, 0.f);
    __syncthreads();
    // fused next-layer GEMM: M_out-tile = h_tile @ Wn
    f32x4 acc2 = {0,0,0,0};
    const _Float16* hp = &sh[l15*HTS];
    acc2 = __builtin_amdgcn_mfma_f32_16x16x32_f16(*(const h8*)(hp + kgrp*8),      WF2[0], acc2, 0, 0, 0);
    acc2 = __builtin_amdgcn_mfma_f32_16x16x32_f16(*(const h8*)(hp + 32 + kgrp*8), WF2[1], acc2, 0, 0, 0);
    uint2 u;
    u.x = packh2(acc2[0], acc2[1]);
    u.y = packh2(acc2[2], acc2[3]);
    *(uint2*)&ob[(((size_t)nt*13 + ksw)*64 + lh*16 + l15)*8 + jb] = u;
  }
}

// ---------------- kRead: gbuf += h3F @ Wc' chunk; last block finalizes out ---
__global__ __launch_bounds__(256) void kRead(
    const _Float16* __restrict__ h3, const _Float16* __restrict__ wfc,
    float* __restrict__ gbuf, uint32_t* __restrict__ cnt,
    const float* __restrict__ bc, const float* __restrict__ Wl,
    const float* __restrict__ bl, float* __restrict__ out)
{
  __shared__ uint32_t sdone;
  const int tid = threadIdx.x, lane = tid & 63, nt = tid >> 6;
  const int l15 = lane & 15, kgrp = lane >> 4;
  const int rt = blockIdx.x & 15, kc = blockIdx.x >> 4;   // 16 row-tiles x 32 k-chunks
  f32x4 acc = {0,0,0,0};
  const _Float16* hp = h3 + (size_t)(rt*16 + l15)*MTF;
  for (int ks = 0; ks < 26; ++ks) {
    int kt = kc*26 + ks;                                  // < 832
    h8 af = *(const h8*)(hp + kt*32 + kgrp*8);
    h8 bf = *(const h8*)(wfc + (((size_t)kt*4 + nt)*64 + lane)*8);
    acc = __builtin_amdgcn_mfma_f32_16x16x32_f16(af, bf, acc, 0, 0, 0);
  }
  #pragma unroll
  for (int r = 0; r < 4; ++r)
    atomicAdd(&gbuf[(size_t)(rt*16 + kgrp*4 + r)*H + nt*16 + l15], acc[r]);
  __threadfence();
  if (tid == 0)
    sdone = __hip_atomic_fetch_add(cnt, 1u, __ATOMIC_ACQ_REL, __HIP_MEMORY_SCOPE_AGENT);
  __syncthreads();
  if (sdone != 511u) return;

  // ---- final role (last block): out = (gbuf + bc) @ Wl + bl ----
  // coherent (agent-scope) loads: gbuf written by blocks on other XCDs
  const float wl0 = Wl[lane*2 + 0], wl1 = Wl[lane*2 + 1];
  const float bcv = bc[lane];
  for (int gg = nt*64; gg < nt*64 + 64; ++gg) {
    float v = __hip_atomic_load(&gbuf[(size_t)gg*H + lane],
                                __ATOMIC_RELAXED, __HIP_MEMORY_SCOPE_AGENT);
    float s = v + bcv;
    float p0 = s * wl0, p1 = s * wl1;
    #pragma unroll
    for (int d = 1; d < 64; d <<= 1) {
      p0 += __shfl_xor(p0, d);
      p1 += __shfl_xor(p1, d);
    }
    if (lane == 0) {
      out[gg*2 + 0] = p0 + bl[0];
      out[gg*2 + 1] = p1 + bl[1];
    }
  }
}

extern "C" void kernel_launch(void* const* d_in, const int* in_sizes, int n_in,
                              void* d_out, int out_size, void* d_ws, size_t ws_size,
                              hipStream_t stream)
{
  const float* x  = (const float*)d_in[0];
  const int*   ei = (const int*)d_in[1];
  const float* ew = (const float*)d_in[2];
  const float* W1 = (const float*)d_in[3];
  const float* b1 = (const float*)d_in[4];
  const float* W2 = (const float*)d_in[5];
  const float* b2 = (const float*)d_in[6];
  const float* W3 = (const float*)d_in[7];
  const float* b3 = (const float*)d_in[8];
  const float* Wc = (const float*)d_in[9];
  const float* bc = (const float*)d_in[10];
  const float* Wl = (const float*)d_in[11];
  const float* bl = (const float*)d_in[12];
  float* out = (float*)d_out;
  (void)ws_size;

  char* ws = (char*)d_ws;
  size_t o = 0;
  uint32_t*  ent   = (uint32_t*)(ws + o);  o += (size_t)G*CPG*4;        // 13.5 MB
  uint32_t*  boff  = (uint32_t*)(ws + o);  o += (size_t)G*32*4;         // 32 KB
  _Float16*  mtA   = (_Float16*)(ws + o);  o += (size_t)G*MTF*2 + 256;  // 13.6 MB
  _Float16*  mtB   = (_Float16*)(ws + o);  o += (size_t)G*MTF*2 + 256;  // 13.6 MB
  _Float16*  wf    = (_Float16*)(ws + o);  o += (size_t)WF_TOT*2;       // 3.5 MB
  float*     gbuf  = (float*)(ws + o);     o += (size_t)G*H*4;          // 64 KB
  uint32_t*  cnt   = (uint32_t*)(ws + o);  o += 256;

  kFront<<<256 + WF_TOT/1024, 1024, 0, stream>>>(ei, ew, W1, W2, W3, Wc,
                                                 ent, boff, wf, gbuf, cnt);
  kM1<<<dim3(7, G), 256, 0, stream>>>(x, wf, mtA);
  const int aggLds = 16*ATS*4 + 16*HTS*2;   // 26880 + 2304 = 29184 B
  kAgg<1><<<NTILE*G, 256, aggLds, stream>>>(mtA, wf + W2F_OFF, b1, ent, boff, mtB);
  kAgg<1><<<NTILE*G, 256, aggLds, stream>>>(mtB, wf + W3F_OFF, b2, ent, boff, mtA);
  kAgg<0><<<NTILE*G, 256, aggLds, stream>>>(mtA, wf, b3, ent, boff, mtB);
  kRead<<<512, 256, 0, stream>>>(mtB, wf + WCF_OFF, gbuf, cnt, bc, Wl, bl, out);
}

// Round 16
// 250.056 us; speedup vs baseline: 1.2822x; 1.2822x over previous
//
#include <hip/hip_runtime.h>
#include <hip/hip_bf16.h>
#include <stdint.h>

#define G 256
#define NPG 400
#define DEG 32
#define FIN 400
#define H 64
#define NN (G*NPG)        // 102400
#define EE (G*NPG*DEG)    // 3276800
#define EPG (NPG*DEG)     // 12800 edges per graph
#define CPG (EPG+NPG)     // 13200 entries per graph (edges + self loops)
#define NTILE 25          // 16-row dst tiles per graph (25x16 = 400 exactly)
#define ATS 420           // A-tile LDS stride (floats)
#define HTS 72            // h-tile LDS stride (halves)
#define MTF 26624         // per-graph M fragment-order elems: 4nt*13ks*64lane*8j

// wf buffer layout (halves)
#define W1F_OFF 0
#define W1F_N   (13*4*64*8)          // 26624
#define W2F_OFF (W1F_OFF + W1F_N)    // 26624
#define W2F_N   (2*4*64*8)           // 4096
#define W3F_OFF (W2F_OFF + W2F_N)    // 30720
#define WCF_OFF (W3F_OFF + W2F_N)    // 34816
#define WCF_N   (832*4*64*8)         // 1703936  (K' = 26624 = 832 kt-chunks)
#define WF_TOT  (WCF_OFF + WCF_N)    // 1738752

typedef __attribute__((ext_vector_type(8))) _Float16 h8;
typedef __attribute__((ext_vector_type(4))) float f32x4;

static __device__ __forceinline__ unsigned packh2(float a, float b) {
  unsigned short ua = __builtin_bit_cast(unsigned short, (_Float16)a);
  unsigned short ub = __builtin_bit_cast(unsigned short, (_Float16)b);
  return (unsigned)ua | ((unsigned)ub << 16);
}

static __device__ __forceinline__ h8 cvt8(float4 a, float4 b) {
  h8 r;
  r[0] = (_Float16)a.x; r[1] = (_Float16)a.y; r[2] = (_Float16)a.z; r[3] = (_Float16)a.w;
  r[4] = (_Float16)b.x; r[5] = (_Float16)b.y; r[6] = (_Float16)b.z; r[7] = (_Float16)b.w;
  return r;
}

// ---------------- kPack: all weights -> fp16 B-frag order --------------------
__global__ __launch_bounds__(256) void kPack(
    const float* __restrict__ W1, const float* __restrict__ W2,
    const float* __restrict__ W3, const float* __restrict__ Wc,
    _Float16* __restrict__ wf)
{
  int idx = blockIdx.x*256 + threadIdx.x;
  if (idx >= WF_TOT) return;
  if (idx < W2F_OFF) {                       // W1: [ks 13][nt 4][lane][j]
    int i = idx;
    int j = i & 7, ln = (i >> 3) & 63, nt = (i >> 9) & 3, ks = i >> 11;
    int k = ks*32 + (ln >> 4)*8 + j, col = nt*16 + (ln & 15);
    wf[idx] = (k < FIN) ? (_Float16)W1[k*H + col] : (_Float16)0.f;
  } else if (idx < W3F_OFF) {                // W2: [ks 2][nt 4][lane][j]
    int i = idx - W2F_OFF;
    int j = i & 7, ln = (i >> 3) & 63, nt = (i >> 9) & 3, ks = i >> 11;
    wf[idx] = (_Float16)W2[(ks*32 + (ln >> 4)*8 + j)*H + nt*16 + (ln & 15)];
  } else if (idx < WCF_OFF) {                // W3
    int i = idx - W3F_OFF;
    int j = i & 7, ln = (i >> 3) & 63, nt = (i >> 9) & 3, ks = i >> 11;
    wf[idx] = (_Float16)W3[(ks*32 + (ln >> 4)*8 + j)*H + nt*16 + (ln & 15)];
  } else {                                   // Wc, k' = mtF flat index
    int i = idx - WCF_OFF;
    int j = i & 7, ln = (i >> 3) & 63, ntc = (i >> 9) & 3, kt = i >> 11;
    int kp = kt*32 + (ln >> 4)*8 + j;        // 0..26623 (mtF flat)
    int nt_m = kp / 6656, rem = kp % 6656;   // 6656 = 13*512
    int ks_m = rem >> 9, rem2 = rem & 511;
    int lane_m = rem2 >> 3, j_m = rem2 & 7;
    int node = ks_m*32 + (lane_m >> 4)*8 + j_m;
    int feat = nt_m*16 + (lane_m & 15);
    int col = ntc*16 + (ln & 15);
    wf[idx] = (node < NPG) ? (_Float16)Wc[((size_t)node*64 + feat)*64 + col]
                           : (_Float16)0.f;
  }
}

// ---------------- kNorm: degree + packed 4B entries bucketed by 16-row tile --
// entry = dstLocal[29:26] | src[25:16] | fp16(norm)[15:0]
__global__ __launch_bounds__(1024) void kNorm(
    const int* __restrict__ ei, const float* __restrict__ ew,
    uint32_t* __restrict__ ent, uint32_t* __restrict__ boff)
{
  __shared__ float deg[NPG];
  __shared__ float dv[NPG];
  __shared__ uint32_t bcnt[32], bpos[32];
  const int g = blockIdx.x, tid = threadIdx.x;
  const int ebase = g*EPG, nbase = g*NPG;
  const int* rowp = ei;          // sources
  const int* colp = ei + EE;     // targets
  if (tid < NTILE) bcnt[tid] = 0u;
  for (int v = tid; v < NPG; v += 1024) deg[v] = 1.0f;   // self-loop weight
  __syncthreads();
  for (int e = tid; e < EPG; e += 1024) {
    int c = colp[ebase+e] - nbase;
    atomicAdd(&deg[c], ew[ebase+e]);
    atomicAdd(&bcnt[c >> 4], 1u);
  }
  __syncthreads();
  for (int v = tid; v < NPG; v += 1024) dv[v] = rsqrtf(deg[v]);
  if (tid == 0) {
    uint32_t s = 0;
    #pragma unroll
    for (int t = 0; t < NTILE; ++t) {
      uint32_t c = bcnt[t] + 16u;              // + 16 self loops per tile
      bcnt[t] = s; bpos[t] = s; s += c;
    }
  }
  __syncthreads();
  if (tid < NTILE) boff[g*32 + tid] = bcnt[tid];
  if (tid == NTILE) boff[g*32 + NTILE] = (uint32_t)CPG;
  uint32_t* eb = ent + (size_t)g*CPG;
  for (int e = tid; e < EPG; e += 1024) {
    int src = rowp[ebase+e] - nbase;
    int dst = colp[ebase+e] - nbase;
    float nm = dv[src] * ew[ebase+e] * dv[dst];
    unsigned short nb = __builtin_bit_cast(unsigned short, (_Float16)nm);
    uint32_t p = atomicAdd(&bpos[dst >> 4], 1u);
    eb[p] = ((unsigned)(dst & 15) << 26) | ((unsigned)src << 16) | nb;
  }
  for (int v = tid; v < NPG; v += 1024) {
    float nm = dv[v]*dv[v];
    unsigned short nb = __builtin_bit_cast(unsigned short, (_Float16)nm);
    uint32_t p = atomicAdd(&bpos[v >> 4], 1u);
    eb[p] = ((unsigned)(v & 15) << 26) | ((unsigned)v << 16) | nb;
  }
}

// ---------------- kM1: mtF1 = frag-order (x @ W1), fp16, no LDS --------------
__global__ __launch_bounds__(256, 8) void kM1(
    const float* __restrict__ x, const _Float16* __restrict__ wf,
    _Float16* __restrict__ mt1)
{
  const int tid = threadIdx.x, lane = tid & 63, wave = tid >> 6;
  const int l15 = lane & 15, kgrp = lane >> 4;
  const int g = blockIdx.y, b = blockIdx.x;  // b < 7, nodes b*64..b*64+63
  const int node_l = b*64 + wave*16 + l15;
  const int arow = (node_l < NPG) ? node_l : NPG-1;
  const float* xp = x + ((size_t)g*NPG + arow)*FIN;

  f32x4 acc[4] = {{0,0,0,0},{0,0,0,0},{0,0,0,0},{0,0,0,0}};
  for (int ks = 0; ks < 13; ++ks) {
    const int kb = ks*32 + kgrp*8;
    h8 af;
    if (kb + 8 <= FIN) {
      float4 a0 = *(const float4*)(xp + kb);
      float4 a1 = *(const float4*)(xp + kb + 4);
      af = cvt8(a0, a1);
    } else {
      h8 z;
      #pragma unroll
      for (int j = 0; j < 8; ++j) z[j] = (_Float16)0.f;
      af = z;
    }
    #pragma unroll
    for (int nt = 0; nt < 4; ++nt) {
      h8 bf = *(const h8*)&wf[W1F_OFF + (((size_t)ks*4 + nt)*64 + lane)*8];
      acc[nt] = __builtin_amdgcn_mfma_f32_16x16x32_f16(af, bf, acc[nt], 0, 0, 0);
    }
  }
  // direct fragment-order write: D row = kgrp*4+r -> node; col = nt*16+l15
  const int nd0 = b*64 + wave*16 + kgrp*4;
  if (nd0 < NPG) {
    const int ksw = nd0 >> 5, lh = (nd0 >> 3) & 3, jb = nd0 & 7;
    _Float16* mb = mt1 + (size_t)g*MTF;
    #pragma unroll
    for (int nt = 0; nt < 4; ++nt) {
      uint2 u;
      u.x = packh2(acc[nt][0], acc[nt][1]);
      u.y = packh2(acc[nt][2], acc[nt][3]);
      *(uint2*)&mb[(((size_t)nt*13 + ksw)*64 + lh*16 + l15)*8 + jb] = u;
    }
  }
}

// ---------------- kAgg<WMUL>: one 16-row dst tile: scatter + agg MFMA --------
template<int WMUL>
__global__ __launch_bounds__(256, 4) void kAgg(
    const _Float16* __restrict__ mtin, const _Float16* __restrict__ wfn,
    const float* __restrict__ bias,
    const uint32_t* __restrict__ ent, const uint32_t* __restrict__ boff,
    _Float16* __restrict__ out)
{
  extern __shared__ char smem[];
  float* sAT = (float*)smem;                     // 16*420*4 = 26880 B
  _Float16* sh = (_Float16*)(smem + 16*ATS*4);   // 16*72*2  = 2304 B
  const int tid = threadIdx.x, lane = tid & 63;
  const int l15 = lane & 15, kgrp = lane >> 4;
  const int bid = blockIdx.x;
  const int g = bid & 255, t = bid >> 8;         // same-graph blocks share XCD
  const int nt = tid >> 6;                       // wave = output col quarter
  const uint32_t* eb = ent + (size_t)g*CPG;
  const uint32_t s0 = boff[g*32 + t], s1 = boff[g*32 + t + 1];

  // coalesced BF prefetch: 13 x 1KB wave loads (frag-order mt)
  h8 BF[13];
  const _Float16* mrow = mtin + (size_t)g*MTF + (size_t)nt*13*512 + lane*8;
  #pragma unroll
  for (int ks = 0; ks < 13; ++ks)
    BF[ks] = *(const h8*)(mrow + ks*512);
  const float bv = bias[nt*16 + l15];
  h8 WF2[2];
  if (WMUL) {
    WF2[0] = *(const h8*)&wfn[((size_t)(0*4 + nt)*64 + lane)*8];
    WF2[1] = *(const h8*)&wfn[((size_t)(1*4 + nt)*64 + lane)*8];
  }
  const uint32_t e0 = s0 + tid;
  uint32_t E0 = 0, E1 = 0, E2 = 0;
  bool p0 = e0 < s1, p1 = e0 + 256 < s1, p2 = e0 + 512 < s1;
  if (p0) E0 = eb[e0];
  if (p1) E1 = eb[e0 + 256];
  if (p2) E2 = eb[e0 + 512];

  // zero A-tile
  { float4* p = (float4*)sAT;
    for (int i = tid; i < 16*ATS/4; i += 256) p[i] = make_float4(0,0,0,0); }
  __syncthreads();

  // scatter: addr = dstLocal*ATS + src, weight = fp16 bits
  if (p0) atomicAdd(&sAT[(int)(E0 >> 26)*ATS + (int)((E0 >> 16) & 0x3FFu)],
                    (float)__builtin_bit_cast(_Float16, (unsigned short)(E0 & 0xFFFFu)));
  if (p1) atomicAdd(&sAT[(int)(E1 >> 26)*ATS + (int)((E1 >> 16) & 0x3FFu)],
                    (float)__builtin_bit_cast(_Float16, (unsigned short)(E1 & 0xFFFFu)));
  if (p2) atomicAdd(&sAT[(int)(E2 >> 26)*ATS + (int)((E2 >> 16) & 0x3FFu)],
                    (float)__builtin_bit_cast(_Float16, (unsigned short)(E2 & 0xFFFFu)));
  for (uint32_t e = e0 + 768; e < s1; e += 256) {      // overflow guard
    uint32_t E = eb[e];
    atomicAdd(&sAT[(int)(E >> 26)*ATS + (int)((E >> 16) & 0x3FFu)],
              (float)__builtin_bit_cast(_Float16, (unsigned short)(E & 0xFFFFu)));
  }
  __syncthreads();

  // agg MFMA: 16 nodes x 16 cols per wave
  f32x4 acc = {0,0,0,0};
  const float* ap = &sAT[l15*ATS];
  #pragma unroll
  for (int ks = 0; ks < 13; ++ks) {
    int kb = ks*32 + kgrp*8;
    float4 a0 = *(const float4*)(ap + kb);
    float4 a1 = *(const float4*)(ap + kb + 4);
    acc = __builtin_amdgcn_mfma_f32_16x16x32_f16(cvt8(a0, a1), BF[ks], acc, 0, 0, 0);
  }

  // fragment-order write coords for output node block
  const int nd0 = t*16 + kgrp*4;               // < 400 always
  const int ksw = nd0 >> 5, lh = (nd0 >> 3) & 3, jb = nd0 & 7;
  _Float16* ob = out + (size_t)g*MTF;

  if (!WMUL) {
    uint2 u;
    u.x = packh2(acc[0] + bv, acc[1] + bv);
    u.y = packh2(acc[2] + bv, acc[3] + bv);
    *(uint2*)&ob[(((size_t)nt*13 + ksw)*64 + lh*16 + l15)*8 + jb] = u;
  } else {
    // bias + relu -> h-tile LDS
    #pragma unroll
    for (int r = 0; r < 4; ++r)
      sh[(kgrp*4 + r)*HTS + nt*16 + l15] = (_Float16)fmaxf(acc[r] + bv, 0.f);
    __syncthreads();
    // fused next-layer GEMM: M_out-tile = h_tile @ Wn
    f32x4 acc2 = {0,0,0,0};
    const _Float16* hp = &sh[l15*HTS];
    acc2 = __builtin_amdgcn_mfma_f32_16x16x32_f16(*(const h8*)(hp + kgrp*8),      WF2[0], acc2, 0, 0, 0);
    acc2 = __builtin_amdgcn_mfma_f32_16x16x32_f16(*(const h8*)(hp + 32 + kgrp*8), WF2[1], acc2, 0, 0, 0);
    uint2 u;
    u.x = packh2(acc2[0], acc2[1]);
    u.y = packh2(acc2[2], acc2[3]);
    *(uint2*)&ob[(((size_t)nt*13 + ksw)*64 + lh*16 + l15)*8 + jb] = u;
  }
}

// ---------------- kRead: gpart[kc] = h3F[16 graphs] @ Wc' chunk (no atomics) -
__global__ __launch_bounds__(256) void kRead(
    const _Float16* __restrict__ h3, const _Float16* __restrict__ wfc,
    float* __restrict__ gpart)
{
  const int tid = threadIdx.x, lane = tid & 63, nt = tid >> 6;
  const int l15 = lane & 15, kgrp = lane >> 4;
  const int rt = blockIdx.x & 15, kc = blockIdx.x >> 4;   // 16 row-tiles x 32 k-chunks
  f32x4 acc = {0,0,0,0};
  const _Float16* hp = h3 + (size_t)(rt*16 + l15)*MTF;
  for (int ks = 0; ks < 26; ++ks) {
    int kt = kc*26 + ks;                                  // < 832
    h8 af = *(const h8*)(hp + kt*32 + kgrp*8);
    h8 bf = *(const h8*)(wfc + (((size_t)kt*4 + nt)*64 + lane)*8);
    acc = __builtin_amdgcn_mfma_f32_16x16x32_f16(af, bf, acc, 0, 0, 0);
  }
  #pragma unroll
  for (int r = 0; r < 4; ++r)
    gpart[((size_t)(kc*16 + rt)*16 + kgrp*4 + r)*64 + nt*16 + l15] = acc[r];
}

// ---------------- k6: out[g] = (sum_kc gpart + bc) @ Wl + bl -----------------
__global__ __launch_bounds__(64) void k6_final(
    const float* __restrict__ gpart, const float* __restrict__ bc,
    const float* __restrict__ Wl, const float* __restrict__ bl,
    float* __restrict__ out)
{
  const int g = blockIdx.x, f = threadIdx.x;   // 256 blocks x 64 threads
  float s = bc[f];
  #pragma unroll 4
  for (int kc = 0; kc < 32; ++kc)
    s += gpart[((size_t)(kc*16 + (g >> 4))*16 + (g & 15))*64 + f];
  float p0 = s * Wl[f*2 + 0];
  float p1 = s * Wl[f*2 + 1];
  #pragma unroll
  for (int d = 1; d < 64; d <<= 1) {
    p0 += __shfl_xor(p0, d);
    p1 += __shfl_xor(p1, d);
  }
  if (f == 0) {
    out[g*2 + 0] = p0 + bl[0];
    out[g*2 + 1] = p1 + bl[1];
  }
}

extern "C" void kernel_launch(void* const* d_in, const int* in_sizes, int n_in,
                              void* d_out, int out_size, void* d_ws, size_t ws_size,
                              hipStream_t stream)
{
  const float* x  = (const float*)d_in[0];
  const int*   ei = (const int*)d_in[1];
  const float* ew = (const float*)d_in[2];
  const float* W1 = (const float*)d_in[3];
  const float* b1 = (const float*)d_in[4];
  const float* W2 = (const float*)d_in[5];
  const float* b2 = (const float*)d_in[6];
  const float* W3 = (const float*)d_in[7];
  const float* b3 = (const float*)d_in[8];
  const float* Wc = (const float*)d_in[9];
  const float* bc = (const float*)d_in[10];
  const float* Wl = (const float*)d_in[11];
  const float* bl = (const float*)d_in[12];
  float* out = (float*)d_out;
  (void)ws_size;

  char* ws = (char*)d_ws;
  size_t o = 0;
  uint32_t*  ent   = (uint32_t*)(ws + o);  o += (size_t)G*CPG*4;        // 13.5 MB
  uint32_t*  boff  = (uint32_t*)(ws + o);  o += (size_t)G*32*4;         // 32 KB
  _Float16*  mtA   = (_Float16*)(ws + o);  o += (size_t)G*MTF*2 + 256;  // 13.6 MB
  _Float16*  mtB   = (_Float16*)(ws + o);  o += (size_t)G*MTF*2 + 256;  // 13.6 MB
  _Float16*  wf    = (_Float16*)(ws + o);  o += (size_t)WF_TOT*2;       // 3.5 MB
  float*     gpart = (float*)(ws + o);     o += (size_t)32*G*H*4;       // 2 MB

  kPack<<<(WF_TOT+255)/256, 256, 0, stream>>>(W1, W2, W3, Wc, wf);
  kNorm<<<G, 1024, 0, stream>>>(ei, ew, ent, boff);
  kM1<<<dim3(7, G), 256, 0, stream>>>(x, wf, mtA);
  const int aggLds = 16*ATS*4 + 16*HTS*2;   // 26880 + 2304 = 29184 B
  kAgg<1><<<NTILE*G, 256, aggLds, stream>>>(mtA, wf + W2F_OFF, b1, ent, boff, mtB);
  kAgg<1><<<NTILE*G, 256, aggLds, stream>>>(mtB, wf + W3F_OFF, b2, ent, boff, mtA);
  kAgg<0><<<NTILE*G, 256, aggLds, stream>>>(mtA, wf, b3, ent, boff, mtB);
  kRead<<<512, 256, 0, stream>>>(mtB, wf + WCF_OFF, gpart);
  k6_final<<<G, 64, 0, stream>>>(gpart, bc, Wl, bl, out);
}